// Round 1
// baseline (45097.131 us; speedup 1.0000x reference)
//
#include <hip/hip_runtime.h>
#include <math.h>

#define T_DATA 30000
#define E_NO   1000
#define I_NO   250
#define SUBN   20
#define NB     13
#define KLEN   81            // basis support: lags 0..80 (all taps >80 are exactly 0)
#define CH     128           // scan chunk (steps)
#define NCHUNK 235           // ceil(30000/128)
#define T_PAD  (NCHUNK*CH)   // 30080

// ws layout (float offsets)
#define SYN_OFF  0
#define UPAD_OFF (T_PAD*SUBN)              // 601600
#define SE_OFF   (UPAD_OFF + T_PAD*SUBN)   // 1203200
#define SI_OFF   (SE_OFF + T_DATA*SUBN)    // 1803200
#define FK_OFF   (SI_OFF + T_DATA*SUBN)    // 2403200  fkern [s][d][2] = {ek, ik}
#define KS_OFF   (FK_OFF + SUBN*KLEN*2)    // 2406440  kscat [s][79+1][2] = {hk,pk}, taps d=1..80
#define KD0_OFF  (KS_OFF + SUBN*80*2)      // 2409640  kd0 [s][2] = {hk[0], pk[0]}
// total 2409680 floats = ~9.6 MB of d_ws

// ---------------- Phase A: column sums mod 20 (exact integer sums) ----------------
__global__ void colsum_kernel(const float* __restrict__ Se, const float* __restrict__ Si,
                              float* __restrict__ ws){
  int t = blockIdx.x;
  int which = blockIdx.y;
  const float* src = which ? Si : Se;
  int n = which ? I_NO : E_NO;
  float* dst = ws + (which ? SI_OFF : SE_OFF) + (size_t)t*SUBN;
  __shared__ float acc[SUBN];
  if (threadIdx.x < SUBN) acc[threadIdx.x] = 0.f;
  __syncthreads();
  const float* row = src + (size_t)t*n;
  for (int e = threadIdx.x; e < n; e += blockDim.x){
    float v = row[e];
    if (v != 0.f) atomicAdd(&acc[e % SUBN], v);   // adds of 1.0: exact, order-independent
  }
  __syncthreads();
  if (threadIdx.x < SUBN) dst[threadIdx.x] = acc[threadIdx.x];
}

// ---------------- U copy with padding to chunk multiple ----------------
__global__ void ucopy_kernel(const float* __restrict__ U, float* __restrict__ ws){
  int i = blockIdx.x*blockDim.x + threadIdx.x;
  if (i < T_PAD*SUBN) ws[UPAD_OFF + i] = (i < T_DATA*SUBN) ? U[i] : 1.0e30f;
}

// ---------------- Phase B: basis + kernels (mimic numpy f32 op order) ----------------
__global__ void buildkern_kernel(const float* __restrict__ Wsyn, const float* __restrict__ Whist,
                                 const float* __restrict__ Wprop, float* __restrict__ ws){
  __shared__ float basis[NB][KLEN];
  const float PI_F = 3.14159265358979323846f;
  const float HALF_PI_F = 1.57079632679489661923f;
  int tid = threadIdx.x;
  for (int i = tid; i < NB*KLEN; i += 256){
    int b = i / KLEN, x = i - b*KLEN;
    float phi = HALF_PI_F * (float)b;
    float raw = 5.0f * logf((float)x + 1.0f + 1e-08f);
    float v = 0.5f * cosf(raw - phi) + 0.5f;
    basis[b][x] = (raw >= phi - PI_F && raw <= phi + PI_F) ? v : 0.f;
  }
  __syncthreads();
  for (int i = tid; i < SUBN*KLEN; i += 256){
    int s = i / KLEN, d = i - s*KLEN;
    float ek=0.f, ik=0.f, hk=0.f, pk=0.f;
    for (int b=0;b<NB;b++){
      float bb = basis[b][d];
      ek += Wsyn[(s*NB + b)*2 + 0] * bb;
      ik += Wsyn[(s*NB + b)*2 + 1] * bb;
      hk += Whist[s*NB + b] * bb;
      pk += Wprop[s*NB + b] * bb;
    }
    ws[FK_OFF + (s*KLEN + d)*2 + 0] = ek;
    ws[FK_OFF + (s*KLEN + d)*2 + 1] = ik;
    if (d == 0){
      ws[KD0_OFF + s*2 + 0] = hk;
      ws[KD0_OFF + s*2 + 1] = pk;
    } else {
      ws[KS_OFF + (s*80 + (d-1))*2 + 0] = hk;
      ws[KS_OFF + (s*80 + (d-1))*2 + 1] = pk;
    }
  }
}

// ---------------- Phase C: 81-tap causal depthwise filter ----------------
__global__ void filter_kernel(float* __restrict__ ws){
  int idx = blockIdx.x*blockDim.x + threadIdx.x;    // t*20 + s
  if (idx >= T_DATA*SUBN) return;
  int t = idx / SUBN;
  int s = idx - t*SUBN;
  const float* fk = ws + FK_OFF + s*(KLEN*2);
  float ae=0.f, ai=0.f;
  int dmax = t < (KLEN-1) ? t : (KLEN-1);
  for (int d=0; d<=dmax; d++){
    ae = fmaf(fk[d*2+0], ws[SE_OFF + idx - d*SUBN], ae);
    ai = fmaf(fk[d*2+1], ws[SI_OFF + idx - d*SUBN], ai);
  }
  ws[SYN_OFF + idx] = ae + ai;
}

// ---------------- Phase D: sequential scan, single wave ----------------
__global__ __launch_bounds__(64,1)
void scan_kernel(const float* __restrict__ ws, const float* __restrict__ Theta,
                 const float* __restrict__ Cden, float* __restrict__ out){
  // acc arrays: stride 218 floats per sub (218 mod 32 = 26 -> consume reads near-conflict-free)
  __shared__ float2 accH2[SUBN][109];
  __shared__ float2 accP2[SUBN][109];
  __shared__ float4 kpad4[SUBN][42];     // kpad[s][m] (float2): m=0 ->0, m=1..80 -> tap m {hk,pk}, 81..83 -> 0
  __shared__ float4 synb4[CH*SUBN/4];
  __shared__ float4 ub4[CH*SUBN/4];
  float* accH = (float*)accH2;
  float* accP = (float*)accP2;
  float2* kpad2 = (float2*)kpad4;        // stride 84 float2 per sub
  float* synb = (float*)synb4;
  float* ub   = (float*)ub4;

  const int lane = threadIdx.x;

  for (int i = lane; i < SUBN*109; i += 64){
    ((float2*)accH2)[i] = make_float2(0.f,0.f);
    ((float2*)accP2)[i] = make_float2(0.f,0.f);
  }
  for (int i = lane; i < SUBN*84; i += 64){
    int s0 = i / 84, m = i - s0*84;
    float2 v = make_float2(0.f,0.f);
    if (m >= 1 && m <= 80){
      v.x = ws[KS_OFF + (s0*80 + (m-1))*2 + 0];
      v.y = ws[KS_OFF + (s0*80 + (m-1))*2 + 1];
    }
    kpad2[i] = v;
  }

  const int s  = lane < SUBN ? lane : 0;
  const bool act = lane < SUBN;
  const float th = Theta[s];
  int c1 = -1, c2 = -1;
  for (int c = 0; c < SUBN; c++){
    if (Cden[s*SUBN + c] != 0.f){ if (c1 < 0) c1 = c; else c2 = c; }
  }
  const int c1s = c1 >= 0 ? c1 : 0;
  const int c2s = c2 >= 0 ? c2 : 0;
  const float hk0  = ws[KD0_OFF + s*2 + 0];
  const float pk01 = (c1 >= 0) ? ws[KD0_OFF + c1*2 + 1] : 0.f;
  const float pk02 = (c2 >= 0) ? ws[KD0_OFF + c2*2 + 1] : 0.f;

  const float4* gs4 = (const float4*)(ws + SYN_OFF);
  const float4* gu4 = (const float4*)(ws + UPAD_OFF);
  float4 ps[10], pu[10];
  #pragma unroll
  for (int k=0;k<10;k++){ ps[k] = gs4[lane + 64*k]; pu[k] = gu4[lane + 64*k]; }

  float dprev = 0.f;
  __syncthreads();

  for (int c = 0; c < NCHUNK; c++){
    // stage current chunk regs -> LDS, then issue prefetch of next chunk
    #pragma unroll
    for (int k=0;k<10;k++){ synb4[lane + 64*k] = ps[k]; ub4[lane + 64*k] = pu[k]; }
    if (c+1 < NCHUNK){
      int b4 = (c+1)*(CH*SUBN/4);
      #pragma unroll
      for (int k=0;k<10;k++){ ps[k] = gs4[b4 + lane + 64*k]; pu[k] = gu4[b4 + lane + 64*k]; }
    }
    __syncthreads();

    const int tbase = c*CH;
    const int jmax = (T_DATA - tbase) < CH ? (T_DATA - tbase) : CH;
    float hN = accH[s*218 + 0];
    float pN = accP[s*218 + 0];

    for (int j = 0; j < jmax; j++){
      float hv = hN, pv = pN;
      float pc1 = __shfl(pv, c1s, 64);
      float pc2 = __shfl(pv, c2s, 64);
      float x = synb[j*SUBN + s] + th + hv + dprev
              + (c1 >= 0 ? pc1 : 0.f) + (c2 >= 0 ? pc2 : 0.f);
      float p = 1.f/(1.f + expf(-x));
      bool spike = act && (ub[j*SUBN + s] < p);
      unsigned long long mask = __ballot(spike ? 1 : 0);
      if (act) out[(size_t)(tbase+j)*SUBN + lane] = spike ? 1.f : 0.f;
      // lag-0 contribution for step j+1 kept in registers (shortens critical path)
      dprev = (((mask>>lane)&1ull) ? hk0 : 0.f)
            + (((mask>>c1s)&1ull) ? pk01 : 0.f)
            + (((mask>>c2s)&1ull) ? pk02 : 0.f);
      // zero consumed slot j (reused after shift)
      if (act){ accH[s*218 + j] = 0.f; accP[s*218 + j] = 0.f; }
      // pre-read slot j+1 BEFORE this step's scatter (slot j+1 only needs scatters <= step j-1)
      hN = accH[s*218 + j + 1];
      pN = accP[s*218 + j + 1];

      // scatter lags 1..80 into LDS accumulators, two spiking subs per pass for overlap
      const int A = (j+2) & ~1;       // even base slot; lane l covers slots A+2l, A+2l+1
      unsigned long long m = mask;
      if (lane < 41){
        const int sl = A + 2*lane;
        while (m){
          int sp1 = __builtin_ctzll(m); m &= m-1;
          int sp2 = -1;
          if (m){ sp2 = __builtin_ctzll(m); m &= m-1; }
          float2 k0a,k1a,k0b,k1b;
          if (j & 1){
            float4 kv = kpad4[sp1][lane];
            k0a = make_float2(kv.x,kv.y); k1a = make_float2(kv.z,kv.w);
          } else {
            k0a = kpad2[sp1*84 + 2*lane + 1];
            k1a = kpad2[sp1*84 + 2*lane + 2];
          }
          float2* ha1 = (float2*)&accH[sp1*218 + sl];
          float2* pa1 = (float2*)&accP[sp1*218 + sl];
          float2 h1 = *ha1, q1 = *pa1;
          float2 *ha2=nullptr, *pa2=nullptr; float2 h2, q2;
          if (sp2 >= 0){
            if (j & 1){
              float4 kv = kpad4[sp2][lane];
              k0b = make_float2(kv.x,kv.y); k1b = make_float2(kv.z,kv.w);
            } else {
              k0b = kpad2[sp2*84 + 2*lane + 1];
              k1b = kpad2[sp2*84 + 2*lane + 2];
            }
            ha2 = (float2*)&accH[sp2*218 + sl];
            pa2 = (float2*)&accP[sp2*218 + sl];
            h2 = *ha2; q2 = *pa2;
          }
          h1.x += k0a.x; h1.y += k1a.x;
          q1.x += k0a.y; q1.y += k1a.y;
          *ha1 = h1; *pa1 = q1;
          if (sp2 >= 0){
            h2.x += k0b.x; h2.y += k1b.x;
            q2.x += k0b.y; q2.y += k1b.y;
            *ha2 = h2; *pa2 = q2;
          }
        }
      }
    }

    // shift accumulators: new[k] = old[CH+k] (k<82), zero [82..82+CH)
    __syncthreads();
    for (int i = lane; i < SUBN*82; i += 64){
      int ss = i / 82, k = i - ss*82;
      accH[ss*218 + k] = accH[ss*218 + CH + k];
      accP[ss*218 + k] = accP[ss*218 + CH + k];
    }
    __syncthreads();
    for (int i = lane; i < SUBN*CH; i += 64){
      int ss = i / CH, k = i - ss*CH;
      accH[ss*218 + 82 + k] = 0.f;
      accP[ss*218 + 82 + k] = 0.f;
    }
    __syncthreads();
  }
}

extern "C" void kernel_launch(void* const* d_in, const int* in_sizes, int n_in,
                              void* d_out, int out_size, void* d_ws, size_t ws_size,
                              hipStream_t stream){
  const float* Se    = (const float*)d_in[0];
  const float* Si    = (const float*)d_in[1];
  const float* U     = (const float*)d_in[2];
  const float* Wsyn  = (const float*)d_in[3];
  const float* Whist = (const float*)d_in[4];
  const float* Wprop = (const float*)d_in[5];
  const float* Theta = (const float*)d_in[6];
  const float* Cden  = (const float*)d_in[7];
  float* out = (float*)d_out;
  float* ws  = (float*)d_ws;

  colsum_kernel<<<dim3(T_DATA,2),256,0,stream>>>(Se,Si,ws);
  ucopy_kernel<<<(T_PAD*SUBN)/256,256,0,stream>>>(U,ws);
  buildkern_kernel<<<1,256,0,stream>>>(Wsyn,Whist,Wprop,ws);
  filter_kernel<<<(T_DATA*SUBN+255)/256,256,0,stream>>>(ws);
  scan_kernel<<<1,64,0,stream>>>(ws,Theta,Cden,out);
}

// Round 3
// 11157.965 us; speedup vs baseline: 4.0417x; 4.0417x over previous
//
#include <hip/hip_runtime.h>
#include <math.h>

#define T_DATA 30000
#define E_NO   1000
#define I_NO   250
#define SUBN   20
#define NB     13
#define KLEN   81            // basis support: x = 0..80 (x>80 exactly 0)
#define CH     32            // scan chunk (steps)
#define NCHUNK 938           // ceil(30000/32)
#define T_PAD  (NCHUNK*CH)   // 30016

// ws layout (float offsets)
#define SYN_OFF  0
#define UPAD_OFF (T_PAD*SUBN)               // 600320
#define SE_OFF   (UPAD_OFF + T_PAD*SUBN)    // 1200640
#define SI_OFF   (SE_OFF + T_DATA*SUBN)     // 1800640
#define FK_OFF   (SI_OFF + T_DATA*SUBN)     // 2400640  fkern [s][x][2] = {ek, ik}
#define KS_OFF   (FK_OFF + SUBN*KLEN*2)     // 2403880  [s][x-1][2] = {hk,pk}, x=1..80
#define KD0_OFF  (KS_OFF + SUBN*80*2)       // 2407080  [s][2] = {hk[0], pk[0]}
#define LUT_OFF  (KD0_OFF + SUBN*2)         // 2407120  LUT float2 entries
#define NPOS 21
#define NENT (SUBN*NPOS*16)                 // 6720 entries (float2)

// ---------------- Phase A: column sums mod 20 (exact integer sums) ----------------
__global__ void colsum_kernel(const float* __restrict__ Se, const float* __restrict__ Si,
                              float* __restrict__ ws){
  int t = blockIdx.x;
  int which = blockIdx.y;
  const float* src = which ? Si : Se;
  int n = which ? I_NO : E_NO;
  float* dst = ws + (which ? SI_OFF : SE_OFF) + (size_t)t*SUBN;
  __shared__ float acc[SUBN];
  if (threadIdx.x < SUBN) acc[threadIdx.x] = 0.f;
  __syncthreads();
  const float* row = src + (size_t)t*n;
  for (int e = threadIdx.x; e < n; e += blockDim.x){
    float v = row[e];
    if (v != 0.f) atomicAdd(&acc[e % SUBN], v);   // adds of 1.0: exact
  }
  __syncthreads();
  if (threadIdx.x < SUBN) dst[threadIdx.x] = acc[threadIdx.x];
}

// ---------------- U copy with padding to chunk multiple ----------------
__global__ void ucopy_kernel(const float* __restrict__ U, float* __restrict__ ws){
  int i = blockIdx.x*blockDim.x + threadIdx.x;
  if (i < T_PAD*SUBN) ws[UPAD_OFF + i] = (i < T_DATA*SUBN) ? U[i] : 1.0e30f;
}

// ---------------- Phase B: basis + kernels (numpy f32 op order) ----------------
__global__ void buildkern_kernel(const float* __restrict__ Wsyn, const float* __restrict__ Whist,
                                 const float* __restrict__ Wprop, float* __restrict__ ws){
  __shared__ float basis[NB][KLEN];
  const float PI_F = 3.14159265358979323846f;
  const float HALF_PI_F = 1.57079632679489661923f;
  int tid = threadIdx.x;
  for (int i = tid; i < NB*KLEN; i += 256){
    int b = i / KLEN, x = i - b*KLEN;
    float phi = HALF_PI_F * (float)b;
    float raw = 5.0f * logf((float)x + 1.0f + 1e-08f);
    float v = 0.5f * cosf(raw - phi) + 0.5f;
    basis[b][x] = (raw >= phi - PI_F && raw <= phi + PI_F) ? v : 0.f;
  }
  __syncthreads();
  for (int i = tid; i < SUBN*KLEN; i += 256){
    int s = i / KLEN, d = i - s*KLEN;
    float ek=0.f, ik=0.f, hk=0.f, pk=0.f;
    for (int b=0;b<NB;b++){
      float bb = basis[b][d];
      ek += Wsyn[(s*NB + b)*2 + 0] * bb;
      ik += Wsyn[(s*NB + b)*2 + 1] * bb;
      hk += Whist[s*NB + b] * bb;
      pk += Wprop[s*NB + b] * bb;
    }
    ws[FK_OFF + (s*KLEN + d)*2 + 0] = ek;
    ws[FK_OFF + (s*KLEN + d)*2 + 1] = ik;
    if (d == 0){
      ws[KD0_OFF + s*2 + 0] = hk;
      ws[KD0_OFF + s*2 + 1] = pk;
    } else {
      ws[KS_OFF + (s*80 + (d-1))*2 + 0] = hk;
      ws[KS_OFF + (s*80 + (d-1))*2 + 1] = pk;
    }
  }
}

// ---------------- Phase B2: build 4-bit history LUT ----------------
// H bit b (b=0..83) == z[t-2-b]  (lag 2+b, basis x = 1+b).
// entry[s][pos][pat] = sum over set bits b' of pat of coeff[s][x-1 = 4*pos+b'].
__global__ void lutbuild_kernel(float* __restrict__ ws){
  int idx = blockIdx.x*blockDim.x + threadIdx.x;
  if (idx >= NENT) return;
  int pat = idx & 15;
  int pos = (idx >> 4) % NPOS;
  int s   = idx / (16*NPOS);
  float h = 0.f, p = 0.f;
  for (int b = 0; b < 4; b++){
    if ((pat >> b) & 1){
      int xm1 = 4*pos + b;            // coeff index x-1
      if (xm1 < 80){
        h += ws[KS_OFF + (s*80 + xm1)*2 + 0];
        p += ws[KS_OFF + (s*80 + xm1)*2 + 1];
      }
    }
  }
  ws[LUT_OFF + idx*2 + 0] = h;
  ws[LUT_OFF + idx*2 + 1] = p;
}

// ---------------- Phase C: 81-tap causal depthwise filter ----------------
__global__ void filter_kernel(float* __restrict__ ws){
  int idx = blockIdx.x*blockDim.x + threadIdx.x;    // t*20 + s
  if (idx >= T_DATA*SUBN) return;
  int t = idx / SUBN;
  int s = idx - t*SUBN;
  const float* fk = ws + FK_OFF + s*(KLEN*2);
  float ae=0.f, ai=0.f;
  int dmax = t < (KLEN-1) ? t : (KLEN-1);
  for (int d=0; d<=dmax; d++){
    ae = fmaf(fk[d*2+0], ws[SE_OFF + idx - d*SUBN], ae);
    ai = fmaf(fk[d*2+1], ws[SI_OFF + idx - d*SUBN], ai);
  }
  ws[SYN_OFF + idx] = ae + ai;
}

// ---------------- Phase D: sequential scan, single wave, LUT gather ----------------
__global__ __launch_bounds__(64,1)
void scan_kernel(const float* __restrict__ ws, const float* __restrict__ Theta,
                 const float* __restrict__ Cden, float* __restrict__ out){
  __shared__ float2 lut[NENT];          // 53760 B
  __shared__ float synb[CH*SUBN];       // 2560 B
  __shared__ float ub[CH*SUBN];         // 2560 B

  const int lane = threadIdx.x;
  // load LUT ws -> LDS
  const float2* lutg = (const float2*)(ws + LUT_OFF);
  for (int i = lane; i < NENT; i += 64) lut[i] = lutg[i];

  const int s = lane % SUBN;
  const int g = lane / SUBN;            // 0..2 real groups; 3 = 4 spare lanes (harmless replicas)

  const float th = Theta[s];
  int c1 = -1, c2 = -1;
  for (int c = 0; c < SUBN; c++){
    if (Cden[s*SUBN + c] != 0.f){ if (c1 < 0) c1 = c; else c2 = c; }
  }
  const int c1s = c1 >= 0 ? c1 : 0;
  const int c2s = c2 >= 0 ? c2 : 0;
  const float ch0   = ws[KD0_OFF + s*2 + 0];
  const float cp0c1 = (c1 >= 0) ? ws[KD0_OFF + c1*2 + 1] : 0.f;
  const float cp0c2 = (c2 >= 0) ? ws[KD0_OFF + c2*2 + 1] : 0.f;

  // per-lane LUT bases: group g covers positions 7g .. 7g+6
  int base[7];
  {
    int pos0 = 7 * g;                   // g==3 -> pos0=21: stays in-bounds (reads other sub's
                                        // entries; partials unused)
    #pragma unroll
    for (int k = 0; k < 7; k++){
      int pos = pos0 + k;
      int e = (s*NPOS + pos)*16;
      if (e > NENT - 16) e = 0;         // clamp spare lanes fully in-bounds
      base[k] = e;
    }
  }

  // spike history bits: H01 = bits 0..63, H2 = bits 64..  (bit b = z[t-2-b] for next step's LUT)
  unsigned long long H01 = 0ull;
  unsigned int H2 = 0u;
  unsigned long long maskprev = 0ull;
  float pre_h = 0.f, pre_p = 0.f;       // LUT-gathered lags>=2 for the upcoming step

  const float2* gs2 = (const float2*)(ws + SYN_OFF);
  const float2* gu2 = (const float2*)(ws + UPAD_OFF);
  float2 ps[5], pu[5];
  #pragma unroll
  for (int k=0;k<5;k++){ ps[k] = gs2[lane + 64*k]; pu[k] = gu2[lane + 64*k]; }
  __syncthreads();

  for (int c = 0; c < NCHUNK; c++){
    #pragma unroll
    for (int k=0;k<5;k++){ ((float2*)synb)[lane + 64*k] = ps[k]; ((float2*)ub)[lane + 64*k] = pu[k]; }
    if (c+1 < NCHUNK){
      int b2 = (c+1)*(CH*SUBN/2);
      #pragma unroll
      for (int k=0;k<5;k++){ ps[k] = gs2[b2 + lane + 64*k]; pu[k] = gu2[b2 + lane + 64*k]; }
    }
    __syncthreads();

    const int tbase = c*CH;
    const int jmax = (T_DATA - tbase) < CH ? (T_DATA - tbase) : CH;
    float synCur = synb[s];
    float uCur   = ub[s];

    for (int j = 0; j < jmax; j++){
      // lag-1 corrections from previous step's ballot (registers only)
      float self1 = ((maskprev >> s)   & 1ull) ? ch0   : 0.f;
      float p1    = ((maskprev >> c1s) & 1ull) ? cp0c1 : 0.f;
      float p2    = ((maskprev >> c2s) & 1ull) ? cp0c2 : 0.f;

      float x = synCur + th + pre_h + self1 + pre_p + p1 + p2;
      float p = 1.f/(1.f + expf(-x));
      bool spike = uCur < p;            // lanes>=20 compute replicas; only bits 0..19 consumed
      unsigned long long mask = __ballot(spike ? 1 : 0);
      if (lane < SUBN) out[(size_t)(tbase + j)*SUBN + lane] = spike ? 1.f : 0.f;

      // ---- lookahead: LUT gather of lags 2..85 for step tbase+j+1 (independent of `mask`) ----
      unsigned int Sa = (unsigned int)H01;                                   // bits 0..31
      unsigned int Sb = (unsigned int)(H01 >> 28);                           // bits 28..59
      unsigned int Sc = (unsigned int)((H01 >> 56) | ((unsigned long long)H2 << 8)); // bits 56..87
      unsigned int S = (g == 0) ? Sa : (g == 1) ? Sb : Sc;
      float ah = 0.f, aw = 0.f;
      #pragma unroll
      for (int k = 0; k < 7; k++){
        unsigned int pat = (S >> (4*k)) & 15u;
        float2 e = lut[base[k] + (int)pat];
        ah += e.x; aw += e.y;
      }
      float hsum = ah + __shfl(ah, lane + 20, 64) + __shfl(ah, lane + 40, 64);
      float wsum = aw + __shfl(aw, lane + 20, 64) + __shfl(aw, lane + 40, 64);
      float pc1 = __shfl(wsum, c1s, 64);
      float pc2 = __shfl(wsum, c2s, 64);
      pre_h = hsum;
      pre_p = (c1 >= 0 ? pc1 : 0.f) + (c2 >= 0 ? pc2 : 0.f);

      // shift in this step's own-sub spike bit for the next lookahead
      H2  = (H2 << 1) | (unsigned int)(H01 >> 63);
      H01 = (H01 << 1) | ((mask >> s) & 1ull);
      maskprev = mask;

      // prefetch next step's syn/u (slot (j+1)&31; stale at chunk end, re-read after barrier)
      int jn = (j + 1) & (CH - 1);
      synCur = synb[jn*SUBN + s];
      uCur   = ub[jn*SUBN + s];
    }
  }
}

extern "C" void kernel_launch(void* const* d_in, const int* in_sizes, int n_in,
                              void* d_out, int out_size, void* d_ws, size_t ws_size,
                              hipStream_t stream){
  const float* Se    = (const float*)d_in[0];
  const float* Si    = (const float*)d_in[1];
  const float* U     = (const float*)d_in[2];
  const float* Wsyn  = (const float*)d_in[3];
  const float* Whist = (const float*)d_in[4];
  const float* Wprop = (const float*)d_in[5];
  const float* Theta = (const float*)d_in[6];
  const float* Cden  = (const float*)d_in[7];
  float* out = (float*)d_out;
  float* ws  = (float*)d_ws;

  colsum_kernel<<<dim3(T_DATA,2),256,0,stream>>>(Se,Si,ws);
  ucopy_kernel<<<(T_PAD*SUBN + 255)/256,256,0,stream>>>(U,ws);
  buildkern_kernel<<<1,256,0,stream>>>(Wsyn,Whist,Wprop,ws);
  lutbuild_kernel<<<(NENT + 255)/256,256,0,stream>>>(ws);
  filter_kernel<<<(T_DATA*SUBN + 255)/256,256,0,stream>>>(ws);
  scan_kernel<<<1,64,0,stream>>>(ws,Theta,Cden,out);
}

// Round 4
// 6501.842 us; speedup vs baseline: 6.9361x; 1.7161x over previous
//
#include <hip/hip_runtime.h>
#include <math.h>

#define T_DATA 30000
#define E_NO   1000
#define I_NO   250
#define SUBN   20
#define NB     13
#define KLEN   81            // basis support: x = 0..80
#define CH     32
#define NFULL  937           // full chunks of 32 steps
#define TAILN  16            // 937*32 + 16 = 30000
#define NCHUNK 938
#define T_PAD  (NCHUNK*CH)   // 30016
#define NPOS   21            // pos 0..19 real (x=3+4p+bb), pos 20 = zeros
#define NENT   (SUBN*NPOS*16)   // 6720 float2 entries

// ws float offsets
#define XP_OFF   0                          // float4[T_PAD*SUBN]: {syn+Theta, xlo, xhi, u}
#define SE_OFF   (T_PAD*SUBN*4)             // 2401280
#define SI_OFF   (SE_OFF + T_DATA*SUBN)     // 3001280
#define FK_OFF   (SI_OFF + T_DATA*SUBN)     // 3601280  [s][x][2] = {ek,ik}
#define KS_OFF   (FK_OFF + SUBN*KLEN*2)     // 3604520  [s][x-1][2] = {hk,pk}, x=1..80
#define KD0_OFF  (KS_OFF + SUBN*80*2)       // 3607720  [s][2] = {hk[0],pk[0]}
#define LUT_OFF  (KD0_OFF + SUBN*2)         // 3607760  NENT float2
// total ~3.63M floats ~14.5 MB

// ---------------- column sums mod 20 (exact integer sums) ----------------
__global__ void colsum_kernel(const float* __restrict__ Se, const float* __restrict__ Si,
                              float* __restrict__ ws){
  int t = blockIdx.x;
  int which = blockIdx.y;
  const float* src = which ? Si : Se;
  int n = which ? I_NO : E_NO;
  float* dst = ws + (which ? SI_OFF : SE_OFF) + (size_t)t*SUBN;
  __shared__ float acc[SUBN];
  if (threadIdx.x < SUBN) acc[threadIdx.x] = 0.f;
  __syncthreads();
  const float* row = src + (size_t)t*n;
  for (int e = threadIdx.x; e < n; e += blockDim.x){
    float v = row[e];
    if (v != 0.f) atomicAdd(&acc[e % SUBN], v);
  }
  __syncthreads();
  if (threadIdx.x < SUBN) dst[threadIdx.x] = acc[threadIdx.x];
}

// ---------------- certainty bounds: xlo/xhi = logit(u -/+ band), f64 ----------------
__global__ void bounds_kernel(const float* __restrict__ U, float* __restrict__ ws){
  int i = blockIdx.x*blockDim.x + threadIdx.x;
  if (i >= T_PAD*SUBN) return;
  float uf = (i < T_DATA*SUBN) ? U[i] : 1.0e30f;
  float xl, xh;
  double u = (double)uf;
  if (u >= 1.0){ xl = __builtin_inff(); xh = __builtin_inff(); }
  else {
    double mn = u < 1.0-u ? u : 1.0-u;
    double band = 1e-5 + 4e-5*mn;
    double uh = u + band, ul = u - band;
    xh = (uh >= 1.0) ?  __builtin_inff() : (float)log(uh/(1.0-uh));
    xl = (ul <= 0.0) ? -__builtin_inff() : (float)log(ul/(1.0-ul));
  }
  float* p = ws + XP_OFF + (size_t)i*4;
  p[1] = xl; p[2] = xh; p[3] = uf;
  if (i >= T_DATA*SUBN) p[0] = 0.f;     // pad syn
}

// ---------------- basis + kernels (numpy f32 op order) ----------------
__global__ void buildkern_kernel(const float* __restrict__ Wsyn, const float* __restrict__ Whist,
                                 const float* __restrict__ Wprop, float* __restrict__ ws){
  __shared__ float basis[NB][KLEN];
  const float PI_F = 3.14159265358979323846f;
  const float HALF_PI_F = 1.57079632679489661923f;
  int tid = threadIdx.x;
  for (int i = tid; i < NB*KLEN; i += 256){
    int b = i / KLEN, x = i - b*KLEN;
    float phi = HALF_PI_F * (float)b;
    float raw = 5.0f * logf((float)x + 1.0f + 1e-08f);
    float v = 0.5f * cosf(raw - phi) + 0.5f;
    basis[b][x] = (raw >= phi - PI_F && raw <= phi + PI_F) ? v : 0.f;
  }
  __syncthreads();
  for (int i = tid; i < SUBN*KLEN; i += 256){
    int s = i / KLEN, d = i - s*KLEN;
    float ek=0.f, ik=0.f, hk=0.f, pk=0.f;
    for (int b=0;b<NB;b++){
      float bb = basis[b][d];
      ek += Wsyn[(s*NB + b)*2 + 0] * bb;
      ik += Wsyn[(s*NB + b)*2 + 1] * bb;
      hk += Whist[s*NB + b] * bb;
      pk += Wprop[s*NB + b] * bb;
    }
    ws[FK_OFF + (s*KLEN + d)*2 + 0] = ek;
    ws[FK_OFF + (s*KLEN + d)*2 + 1] = ik;
    if (d == 0){
      ws[KD0_OFF + s*2 + 0] = hk;
      ws[KD0_OFF + s*2 + 1] = pk;
    } else {
      ws[KS_OFF + (s*80 + (d-1))*2 + 0] = hk;
      ws[KS_OFF + (s*80 + (d-1))*2 + 1] = pk;
    }
  }
}

// ---------------- 4-bit LUT: entry[s][pos][pat] = sum coeff x=3+4*pos+bb ----------------
__global__ void lutbuild_kernel(float* __restrict__ ws){
  int idx = blockIdx.x*blockDim.x + threadIdx.x;
  if (idx >= NENT) return;
  int pat = idx & 15;
  int pos = (idx >> 4) % NPOS;
  int s   = idx / (16*NPOS);
  float h = 0.f, p = 0.f;
  for (int bb = 0; bb < 4; bb++){
    if ((pat >> bb) & 1){
      int x = 3 + 4*pos + bb;
      if (x <= 80){
        h += ws[KS_OFF + (s*80 + (x-1))*2 + 0];
        p += ws[KS_OFF + (s*80 + (x-1))*2 + 1];
      }
    }
  }
  ws[LUT_OFF + idx*2 + 0] = h;
  ws[LUT_OFF + idx*2 + 1] = p;
}

// ---------------- 81-tap causal depthwise filter (+Theta fold) ----------------
__global__ void filter_kernel(const float* __restrict__ Theta, float* __restrict__ ws){
  int idx = blockIdx.x*blockDim.x + threadIdx.x;    // t*20 + s
  if (idx >= T_DATA*SUBN) return;
  int t = idx / SUBN;
  int s = idx - t*SUBN;
  const float* fk = ws + FK_OFF + s*(KLEN*2);
  float ae=0.f, ai=0.f;
  int dmax = t < (KLEN-1) ? t : (KLEN-1);
  for (int d=0; d<=dmax; d++){
    ae = fmaf(fk[d*2+0], ws[SE_OFF + idx - d*SUBN], ae);
    ai = fmaf(fk[d*2+1], ws[SI_OFF + idx - d*SUBN], ai);
  }
  ws[XP_OFF + (size_t)idx*4 + 0] = (ae + ai) + Theta[s];
}

// ---------------- sequential scan: 4-deep pipelined LUT gather, bound-gated sigmoid ----------------
__global__ __launch_bounds__(64,1)
void scan_kernel(const float* __restrict__ ws, const float* __restrict__ Cden,
                 float* __restrict__ out){
  __shared__ float4 xpb[660];           // 10560 B (640 + overrun pad)
  __shared__ float2 lut[NENT];          // 53760 B  -> total 64320 <= 64K

  const int lane = threadIdx.x;
  const int s = lane % SUBN;
  const int g = lane / SUBN;            // 0,1,2 gather groups; 3 = 4 spare lanes
  const bool act = lane < SUBN;

  // load LUT ws->LDS
  const float2* lutg = (const float2*)(ws + LUT_OFF);
  for (int i = lane; i < NENT; i += 64) lut[i] = lutg[i];

  // children from Cden
  int c1 = -1, c2 = -1;
  for (int c = 0; c < SUBN; c++){
    if (Cden[s*SUBN + c] != 0.f){ if (c1 < 0) c1 = c; else c2 = c; }
  }
  const int c1s = c1 >= 0 ? c1 : 0;
  const int c2s = c2 >= 0 ? c2 : 0;
  const float e1f = c1 >= 0 ? 1.f : 0.f;
  const float e2f = c2 >= 0 ? 1.f : 0.f;
  // register coeffs for lags 1..3 (x = 0,1,2)
  const float hk1 = ws[KD0_OFF + s*2 + 0];
  const float hk2 = ws[KS_OFF + (s*80 + 0)*2 + 0];
  const float hk3 = ws[KS_OFF + (s*80 + 1)*2 + 0];
  const float q1a = c1>=0 ? ws[KD0_OFF + c1*2 + 1] : 0.f;
  const float q2a = c1>=0 ? ws[KS_OFF + (c1*80 + 0)*2 + 1] : 0.f;
  const float q3a = c1>=0 ? ws[KS_OFF + (c1*80 + 1)*2 + 1] : 0.f;
  const float q1b = c2>=0 ? ws[KD0_OFF + c2*2 + 1] : 0.f;
  const float q2b = c2>=0 ? ws[KS_OFF + (c2*80 + 0)*2 + 1] : 0.f;
  const float q3b = c2>=0 ? ws[KS_OFF + (c2*80 + 1)*2 + 1] : 0.f;

  // per-lane LUT element bases: group g covers pos 7g..7g+6 (g=3 -> zero row 20)
  int baseE[7];
  {
    int pos0 = 7*g;
    #pragma unroll
    for (int k = 0; k < 7; k++){
      int pos = pos0 + k; if (pos > 20) pos = 20;
      baseE[k] = (s*NPOS + pos)*16;
    }
  }
  // spike-store field: act lanes -> .w; g=1 -> .y, g=2 -> .z, g=3 -> .x (dead fields)
  float* xpbf = (float*)xpb;
  const int sidx = s*4 + (act ? 3 : ((g == 3) ? 0 : g));

  // pipeline state
  float2 rA[7];
  #pragma unroll
  for (int k=0;k<7;k++) rA[k] = make_float2(0.f,0.f);
  float ahp=0.f, awp=0.f, r1h20=0.f, r1h40=0.f, r1w20=0.f, r1w40=0.f;
  float hsumS=0.f, pc1r=0.f, pc2r=0.f;
  float P1=0.f, P2=0.f, P3=0.f;
  unsigned long long H01 = 0ull;
  unsigned int H2 = 0u;

  const float4* gxp = (const float4*)(ws + XP_OFF);
  float4 px[10];
  // prologue: stage chunk 0
  #pragma unroll
  for (int k=0;k<10;k++) px[k] = gxp[k*64 + lane];
  __syncthreads();
  #pragma unroll
  for (int k=0;k<10;k++) xpb[k*64 + lane] = px[k];
  float4 xc = xpb[s];

  #define BODY(J) { \
    float x = xc.x + P1; \
    unsigned long long mask = __ballot(x >= xc.z); \
    bool gap = act && (x >= xc.y) && (x < xc.z); \
    if (__builtin_expect(__any(gap), 0)){ \
      float pp = 1.f/(1.f + expf(-x)); \
      mask = __ballot(xc.w < pp); \
    } \
    unsigned int mlo = (unsigned int)mask; \
    float bsf = (float)((mlo >> s) & 1u); \
    float b1f = (float)((mlo >> c1s) & 1u); \
    float b2f = (float)((mlo >> c2s) & 1u); \
    xpbf[(J)*80 + sidx] = bsf; \
    xc = xpb[((J)+1)*20 + s]; \
    float acc = P2 + hsumS; \
    acc = fmaf(e1f, pc1r, acc); \
    acc = fmaf(e2f, pc2r, acc); \
    acc = fmaf(bsf, hk1, acc); \
    acc = fmaf(b1f, q1a, acc); \
    P1  = fmaf(b2f, q1b, acc); \
    float acc2 = fmaf(bsf, hk2, P3); \
    acc2 = fmaf(b1f, q2a, acc2); \
    P2  = fmaf(b2f, q2b, acc2); \
    float acc3 = bsf*hk3; \
    acc3 = fmaf(b1f, q3a, acc3); \
    P3  = fmaf(b2f, q3b, acc3); \
    hsumS = ahp + r1h20 + r1h40; \
    float wsum = awp + r1w20 + r1w40; \
    pc1r = __shfl(wsum, c1s, 64); \
    pc2r = __shfl(wsum, c2s, 64); \
    float ah = ((rA[0].x + rA[1].x) + (rA[2].x + rA[3].x)) + ((rA[4].x + rA[5].x) + rA[6].x); \
    float aw = ((rA[0].y + rA[1].y) + (rA[2].y + rA[3].y)) + ((rA[4].y + rA[5].y) + rA[6].y); \
    ahp = ah; awp = aw; \
    r1h20 = __shfl(ah, lane + 20, 64); \
    r1h40 = __shfl(ah, lane + 40, 64); \
    r1w20 = __shfl(aw, lane + 20, 64); \
    r1w40 = __shfl(aw, lane + 40, 64); \
    H2  = (H2 << 1) | (unsigned int)(H01 >> 63); \
    H01 = (H01 << 1) | (unsigned long long)((mlo >> s) & 1u); \
    unsigned int Sa = (unsigned int)H01; \
    unsigned int Sb = (unsigned int)(H01 >> 28); \
    unsigned int Sc = (unsigned int)((H01 >> 56) | ((unsigned long long)H2 << 8)); \
    unsigned int S = (g == 0) ? Sa : ((g == 1) ? Sb : Sc); \
    _Pragma("unroll") \
    for (int k = 0; k < 7; k++){ \
      rA[k] = lut[baseE[k] + (int)((S >> (4*k)) & 15u)]; \
    } \
  }

  for (int c = 0; c < NFULL; ++c){
    // prefetch next chunk into regs (latency hidden under 32 steps)
    {
      const float4* gp = gxp + (size_t)(c+1)*640;
      #pragma unroll
      for (int k=0;k<10;k++) px[k] = gp[k*64 + lane];
    }
    #pragma unroll 16
    for (int j = 0; j < CH; ++j) BODY(j);
    // drain spikes (written into .w fields) -> out, coalesced
    {
      float* outb = out + (size_t)c*(CH*SUBN);
      #pragma unroll
      for (int i = 0; i < 10; i++){
        float v = xpbf[(i*64 + lane)*4 + 3];
        outb[i*64 + lane] = v;
      }
    }
    // stage next chunk regs -> LDS, reset xc
    #pragma unroll
    for (int k=0;k<10;k++) xpb[k*64 + lane] = px[k];
    xc = xpb[s];
  }
  // tail: 16 steps
  for (int j = 0; j < TAILN; ++j) BODY(j);
  {
    float* outb = out + (size_t)NFULL*(CH*SUBN);
    #pragma unroll
    for (int i = 0; i < 5; i++){
      float v = xpbf[(i*64 + lane)*4 + 3];
      outb[i*64 + lane] = v;
    }
  }
  #undef BODY
}

extern "C" void kernel_launch(void* const* d_in, const int* in_sizes, int n_in,
                              void* d_out, int out_size, void* d_ws, size_t ws_size,
                              hipStream_t stream){
  const float* Se    = (const float*)d_in[0];
  const float* Si    = (const float*)d_in[1];
  const float* U     = (const float*)d_in[2];
  const float* Wsyn  = (const float*)d_in[3];
  const float* Whist = (const float*)d_in[4];
  const float* Wprop = (const float*)d_in[5];
  const float* Theta = (const float*)d_in[6];
  const float* Cden  = (const float*)d_in[7];
  float* out = (float*)d_out;
  float* ws  = (float*)d_ws;

  colsum_kernel<<<dim3(T_DATA,2),256,0,stream>>>(Se,Si,ws);
  bounds_kernel<<<(T_PAD*SUBN + 255)/256,256,0,stream>>>(U,ws);
  buildkern_kernel<<<1,256,0,stream>>>(Wsyn,Whist,Wprop,ws);
  lutbuild_kernel<<<(NENT + 255)/256,256,0,stream>>>(ws);
  filter_kernel<<<(T_DATA*SUBN + 255)/256,256,0,stream>>>(Theta,ws);
  scan_kernel<<<1,64,0,stream>>>(ws,Cden,out);
}

// Round 5
// 5568.437 us; speedup vs baseline: 8.0987x; 1.1676x over previous
//
#include <hip/hip_runtime.h>
#include <math.h>

#define T_DATA 30000
#define E_NO   1000
#define I_NO   250
#define SUBN   20
#define NB     13
#define KLEN   81            // basis support: x = 0..80 (lags 1..81)
#define CH     32
#define NFULL  937           // full chunks of 32 steps; + tail 16 steps
#define NCHUNK 938
#define T_PAD  (NCHUNK*CH)   // 30016
#define NPOS   20            // pos 0..18 real (lag 6+4p+bb), pos 19 = zero row
#define NENT   (SUBN*NPOS*16)   // 6400 float2 entries

// ws float offsets
#define XP_OFF   0                          // float4[T_PAD*SUBN]: {syn+Theta, xlo, xhi, u}
#define SE_OFF   (T_PAD*SUBN*4)             // 2401280
#define SI_OFF   (SE_OFF + T_DATA*SUBN)     // 3001280
#define FK_OFF   (SI_OFF + T_DATA*SUBN)     // 3601280  [s][x][2] = {ek,ik}
#define KS_OFF   (FK_OFF + SUBN*KLEN*2)     // 3604520  [s][x-1][2] = {hk,pk}, x=1..80 (lag x+1)
#define KD0_OFF  (KS_OFF + SUBN*80*2)       // 3607720  [s][2] = {hk lag1, pk lag1}
#define LUT_OFF  (KD0_OFF + SUBN*2)         // 3607760  NENT float2

// ---------------- column sums mod 20 (exact integer sums) ----------------
__global__ void colsum_kernel(const float* __restrict__ Se, const float* __restrict__ Si,
                              float* __restrict__ ws){
  int t = blockIdx.x;
  int which = blockIdx.y;
  const float* src = which ? Si : Se;
  int n = which ? I_NO : E_NO;
  float* dst = ws + (which ? SI_OFF : SE_OFF) + (size_t)t*SUBN;
  __shared__ float acc[SUBN];
  if (threadIdx.x < SUBN) acc[threadIdx.x] = 0.f;
  __syncthreads();
  const float* row = src + (size_t)t*n;
  for (int e = threadIdx.x; e < n; e += blockDim.x){
    float v = row[e];
    if (v != 0.f) atomicAdd(&acc[e % SUBN], v);
  }
  __syncthreads();
  if (threadIdx.x < SUBN) dst[threadIdx.x] = acc[threadIdx.x];
}

// ---------------- certainty bounds: xlo/xhi = logit(u -/+ band), f64 ----------------
__global__ void bounds_kernel(const float* __restrict__ U, float* __restrict__ ws){
  int i = blockIdx.x*blockDim.x + threadIdx.x;
  if (i >= T_PAD*SUBN) return;
  float uf = (i < T_DATA*SUBN) ? U[i] : 1.0e30f;
  float xl, xh;
  double u = (double)uf;
  if (u >= 1.0){ xl = __builtin_inff(); xh = __builtin_inff(); }
  else {
    double mn = u < 1.0-u ? u : 1.0-u;
    double band = 1e-5 + 4e-5*mn;
    double uh = u + band, ul = u - band;
    xh = (uh >= 1.0) ?  __builtin_inff() : (float)log(uh/(1.0-uh));
    xl = (ul <= 0.0) ? -__builtin_inff() : (float)log(ul/(1.0-ul));
  }
  float* p = ws + XP_OFF + (size_t)i*4;
  p[1] = xl; p[2] = xh; p[3] = uf;
  if (i >= T_DATA*SUBN) p[0] = 0.f;
}

// ---------------- basis + kernels (numpy f32 op order) ----------------
__global__ void buildkern_kernel(const float* __restrict__ Wsyn, const float* __restrict__ Whist,
                                 const float* __restrict__ Wprop, float* __restrict__ ws){
  __shared__ float basis[NB][KLEN];
  const float PI_F = 3.14159265358979323846f;
  const float HALF_PI_F = 1.57079632679489661923f;
  int tid = threadIdx.x;
  for (int i = tid; i < NB*KLEN; i += 256){
    int b = i / KLEN, x = i - b*KLEN;
    float phi = HALF_PI_F * (float)b;
    float raw = 5.0f * logf((float)x + 1.0f + 1e-08f);
    float v = 0.5f * cosf(raw - phi) + 0.5f;
    basis[b][x] = (raw >= phi - PI_F && raw <= phi + PI_F) ? v : 0.f;
  }
  __syncthreads();
  for (int i = tid; i < SUBN*KLEN; i += 256){
    int s = i / KLEN, d = i - s*KLEN;
    float ek=0.f, ik=0.f, hk=0.f, pk=0.f;
    for (int b=0;b<NB;b++){
      float bb = basis[b][d];
      ek += Wsyn[(s*NB + b)*2 + 0] * bb;
      ik += Wsyn[(s*NB + b)*2 + 1] * bb;
      hk += Whist[s*NB + b] * bb;
      pk += Wprop[s*NB + b] * bb;
    }
    ws[FK_OFF + (s*KLEN + d)*2 + 0] = ek;
    ws[FK_OFF + (s*KLEN + d)*2 + 1] = ik;
    if (d == 0){
      ws[KD0_OFF + s*2 + 0] = hk;
      ws[KD0_OFF + s*2 + 1] = pk;
    } else {
      ws[KS_OFF + (s*80 + (d-1))*2 + 0] = hk;
      ws[KS_OFF + (s*80 + (d-1))*2 + 1] = pk;
    }
  }
}

// ---------------- 4-bit LUT for lags >= 6: entry[s][pos][pat], lag = 6+4*pos+bb ----------------
__global__ void lutbuild_kernel(float* __restrict__ ws){
  int idx = blockIdx.x*blockDim.x + threadIdx.x;
  if (idx >= NENT) return;
  int pat = idx & 15;
  int pos = (idx >> 4) % NPOS;
  int s   = idx / (16*NPOS);
  float h = 0.f, p = 0.f;
  for (int bb = 0; bb < 4; bb++){
    if ((pat >> bb) & 1){
      int ksi = 4 + 4*pos + bb;       // KS index = lag-2
      if (ksi <= 79){
        h += ws[KS_OFF + (s*80 + ksi)*2 + 0];
        p += ws[KS_OFF + (s*80 + ksi)*2 + 1];
      }
    }
  }
  ws[LUT_OFF + idx*2 + 0] = h;
  ws[LUT_OFF + idx*2 + 1] = p;
}

// ---------------- 81-tap causal depthwise filter (+Theta fold) ----------------
__global__ void filter_kernel(const float* __restrict__ Theta, float* __restrict__ ws){
  int idx = blockIdx.x*blockDim.x + threadIdx.x;    // t*20 + s
  if (idx >= T_DATA*SUBN) return;
  int t = idx / SUBN;
  int s = idx - t*SUBN;
  const float* fk = ws + FK_OFF + s*(KLEN*2);
  float ae=0.f, ai=0.f;
  int dmax = t < (KLEN-1) ? t : (KLEN-1);
  for (int d=0; d<=dmax; d++){
    ae = fmaf(fk[d*2+0], ws[SE_OFF + idx - d*SUBN], ae);
    ai = fmaf(fk[d*2+1], ws[SI_OFF + idx - d*SUBN], ai);
  }
  ws[XP_OFF + (size_t)idx*4 + 0] = (ae + ai) + Theta[s];
}

// ---------------- 2-wave producer/consumer scan ----------------
#define WGBAR() do{ asm volatile("s_waitcnt lgkmcnt(0)" ::: "memory"); \
                    __builtin_amdgcn_s_barrier(); \
                    __builtin_amdgcn_sched_barrier(0); }while(0)

__global__ __launch_bounds__(128,1)
void scan_kernel(const float* __restrict__ ws, const float* __restrict__ Cden,
                 float* __restrict__ out){
  __shared__ float2 lut[NENT];          // 51200 B
  __shared__ float4 xpb[644];           // 10304 B
  __shared__ float2 part[8*60];         //  3840 B   [slot][g][s]
  __shared__ unsigned int mring[8];     //    32 B
  float* xpbf = (float*)xpb;

  const int tid  = threadIdx.x;
  const int wid  = tid >> 6;
  const int lane = tid & 63;
  const int s = lane % SUBN;
  const int g = lane / SUBN;            // 0..2 real; 3 = spare

  // cooperative init
  {
    const float2* lutg = (const float2*)(ws + LUT_OFF);
    for (int i = tid; i < NENT; i += 128) lut[i] = lutg[i];
    for (int i = tid; i < 8*60; i += 128) part[i] = make_float2(0.f,0.f);
    if (tid < 8) mring[tid] = 0u;
  }

  // children from Cden
  int c1 = -1, c2 = -1;
  for (int c = 0; c < SUBN; c++){
    if (Cden[s*SUBN + c] != 0.f){ if (c1 < 0) c1 = c; else c2 = c; }
  }
  const int c1s = c1 >= 0 ? c1 : 0;
  const int c2s = c2 >= 0 ? c2 : 0;
  const float e1f = c1 >= 0 ? 1.f : 0.f;
  const float e2f = c2 >= 0 ? 1.f : 0.f;

  // register coeffs lags 1..5 (wave0)
  const float hk1 = ws[KD0_OFF + s*2 + 0];
  const float hk2 = ws[KS_OFF + (s*80 + 0)*2 + 0];
  const float hk3 = ws[KS_OFF + (s*80 + 1)*2 + 0];
  const float hk4 = ws[KS_OFF + (s*80 + 2)*2 + 0];
  const float hk5 = ws[KS_OFF + (s*80 + 3)*2 + 0];
  const float q1a = c1>=0 ? ws[KD0_OFF + c1*2 + 1] : 0.f;
  const float q2a = c1>=0 ? ws[KS_OFF + (c1*80 + 0)*2 + 1] : 0.f;
  const float q3a = c1>=0 ? ws[KS_OFF + (c1*80 + 1)*2 + 1] : 0.f;
  const float q4a = c1>=0 ? ws[KS_OFF + (c1*80 + 2)*2 + 1] : 0.f;
  const float q5a = c1>=0 ? ws[KS_OFF + (c1*80 + 3)*2 + 1] : 0.f;
  const float q1b = c2>=0 ? ws[KD0_OFF + c2*2 + 1] : 0.f;
  const float q2b = c2>=0 ? ws[KS_OFF + (c2*80 + 0)*2 + 1] : 0.f;
  const float q3b = c2>=0 ? ws[KS_OFF + (c2*80 + 1)*2 + 1] : 0.f;
  const float q4b = c2>=0 ? ws[KS_OFF + (c2*80 + 2)*2 + 1] : 0.f;
  const float q5b = c2>=0 ? ws[KS_OFF + (c2*80 + 3)*2 + 1] : 0.f;

  // wave1 LUT bases: group g covers pos 7g..7g+6, clamp to zero row 19
  #define POSC(pp) (((pp) > 19) ? 19 : (pp))
  const int baseE0 = (s*NPOS + POSC(7*g+0))*16;
  const int baseE1 = (s*NPOS + POSC(7*g+1))*16;
  const int baseE2 = (s*NPOS + POSC(7*g+2))*16;
  const int baseE3 = (s*NPOS + POSC(7*g+3))*16;
  const int baseE4 = (s*NPOS + POSC(7*g+4))*16;
  const int baseE5 = (s*NPOS + POSC(7*g+5))*16;
  const int baseE6 = (s*NPOS + POSC(7*g+6))*16;

  // spike-stage field (wave0): act lanes -> .w; others write dead fields
  const int sidx = s*4 + ((g == 0) ? 3 : ((g == 3) ? 0 : g));

  const float4* gxp = (const float4*)(ws + XP_OFF);
  float4 px[10];
  if (wid == 0){
    #pragma unroll
    for (int k=0;k<10;k++) px[k] = gxp[k*64 + lane];
  }
  __syncthreads();

  float4 xcur = make_float4(0.f,0.f,0.f,0.f);
  if (wid == 0){
    #pragma unroll
    for (int k=0;k<10;k++) xpb[k*64 + lane] = px[k];
    xcur = xpb[s];
  }

  // persistent state
  float P1=0.f,P2=0.f,P3=0.f,P4=0.f,P5=0.f;
  float extO = 0.f;                     // EXT(next odd-consumed step)
  unsigned long long Hb = 0ull;         // wave1 history bits 0..63
  unsigned int Ht = 0u;                 // bits 64..83
  unsigned int mpo = 0u;                // previous odd mask bit (per-sub)

#define STEP0(Jexpr, MSLOT, EXTIN) { \
  const int J_ = (Jexpr); \
  float x = xcur.x + P1; \
  unsigned long long mk = __ballot(x >= xcur.z); \
  bool gap = (x >= xcur.y) && (x < xcur.z); \
  if (__builtin_expect(__any(gap),0)){ \
    float pp = 1.f/(1.f + expf(-x)); \
    mk = __ballot(xcur.w < pp); \
  } \
  unsigned int mlo = (unsigned int)mk; \
  if (lane == 0) mring[MSLOT] = mlo; \
  float bsf = (float)((mlo >> s)&1u); \
  xpbf[J_*80 + sidx] = bsf; \
  xcur = xpb[(((J_)+1)&31)*20 + s]; \
  float b1f = (float)((mlo >> c1s)&1u); \
  float b2f = (float)((mlo >> c2s)&1u); \
  float a1 = P2 + (EXTIN); \
  a1 = fmaf(bsf,hk1,a1); a1 = fmaf(b1f,q1a,a1); a1 = fmaf(b2f,q1b,a1); \
  float a2 = P3; a2 = fmaf(bsf,hk2,a2); a2 = fmaf(b1f,q2a,a2); a2 = fmaf(b2f,q2b,a2); \
  float a3 = P4; a3 = fmaf(bsf,hk3,a3); a3 = fmaf(b1f,q3a,a3); a3 = fmaf(b2f,q3b,a3); \
  float a4 = P5; a4 = fmaf(bsf,hk4,a4); a4 = fmaf(b1f,q4a,a4); a4 = fmaf(b2f,q4b,a4); \
  float a5 = bsf*hk5; a5 = fmaf(b1f,q5a,a5); a5 = fmaf(b2f,q5b,a5); \
  P1=a1; P2=a2; P3=a3; P4=a4; P5=a5; \
}

#define W0PHASE(u) { \
  const int sl2 = (2*(u)+2)&7, sl3 = (2*(u)+3)&7; \
  float2 A0 = part[sl2*60      + s  ], A1 = part[sl2*60 + 20 + s  ], A2 = part[sl2*60 + 40 + s  ]; \
  float2 B0 = part[sl2*60      + c1s], B1 = part[sl2*60 + 20 + c1s], B2 = part[sl2*60 + 40 + c1s]; \
  float2 C0 = part[sl2*60      + c2s], C1 = part[sl2*60 + 20 + c2s], C2 = part[sl2*60 + 40 + c2s]; \
  float2 D0 = part[sl3*60      + s  ], D1 = part[sl3*60 + 20 + s  ], D2 = part[sl3*60 + 40 + s  ]; \
  float2 E0 = part[sl3*60      + c1s], E1 = part[sl3*60 + 20 + c1s], E2 = part[sl3*60 + 40 + c1s]; \
  float2 F0 = part[sl3*60      + c2s], F1 = part[sl3*60 + 20 + c2s], F2 = part[sl3*60 + 40 + c2s]; \
  STEP0(jb+2*(u),   (2*(u))&7,   extO) \
  float extE2 = fmaf(e2f, (C0.y+C1.y)+C2.y, fmaf(e1f, (B0.y+B1.y)+B2.y, (A0.x+A1.x)+A2.x)); \
  STEP0(jb+2*(u)+1, (2*(u)+1)&7, extE2) \
  extO = fmaf(e2f, (F0.y+F1.y)+F2.y, fmaf(e1f, (E0.y+E1.y)+E2.y, (D0.x+D1.x)+D2.x)); \
}

#define W1PHASE(u) { \
  const int slE = (2*(u)+6)&7, slO = (2*(u)+7)&7; \
  unsigned int mE = mring[slE]; \
  unsigned int mO = mring[slO]; \
  unsigned long long HA01k = (Hb << 2) | ((unsigned long long)(mpo << 1)); \
  unsigned int HA2 = (Ht << 2) | (unsigned int)(Hb >> 62); \
  unsigned int SA = (g==0) ? (unsigned int)HA01k \
                  : ((g==1) ? (unsigned int)(HA01k>>28) \
                            : ((unsigned int)(HA01k>>56) | (HA2<<8))); \
  unsigned long long HB01k = HA01k << 1; \
  unsigned int HB2 = (HA2 << 1) | (unsigned int)(HA01k >> 63); \
  unsigned int SB = (g==0) ? (unsigned int)HB01k \
                  : ((g==1) ? (unsigned int)(HB01k>>28) \
                            : ((unsigned int)(HB01k>>56) | (HB2<<8))); \
  float2 rA0 = lut[baseE0 + (int)( SA      &15u)]; \
  float2 rA1 = lut[baseE1 + (int)((SA>> 4) &15u)]; \
  float2 rA2 = lut[baseE2 + (int)((SA>> 8) &15u)]; \
  float2 rA3 = lut[baseE3 + (int)((SA>>12) &15u)]; \
  float2 rA4 = lut[baseE4 + (int)((SA>>16) &15u)]; \
  float2 rA5 = lut[baseE5 + (int)((SA>>20) &15u)]; \
  float2 rA6 = lut[baseE6 + (int)((SA>>24) &15u)]; \
  float2 rB0 = lut[baseE0 + (int)( SB      &15u)]; \
  float2 rB1 = lut[baseE1 + (int)((SB>> 4) &15u)]; \
  float2 rB2 = lut[baseE2 + (int)((SB>> 8) &15u)]; \
  float2 rB3 = lut[baseE3 + (int)((SB>>12) &15u)]; \
  float2 rB4 = lut[baseE4 + (int)((SB>>16) &15u)]; \
  float2 rB5 = lut[baseE5 + (int)((SB>>20) &15u)]; \
  float2 rB6 = lut[baseE6 + (int)((SB>>24) &15u)]; \
  unsigned int bA = (mE >> s) & 1u; \
  unsigned int bB = (mO >> s) & 1u; \
  if (g == 0){ \
    rA0 = lut[baseE0 + (int)(((SA&15u) | bA))]; \
    rB0 = lut[baseE0 + (int)(bB | (bA<<1) | (mpo<<2) | (((unsigned int)(Hb & 1ull))<<3))]; \
  } \
  float ahA = ((rA0.x+rA1.x)+(rA2.x+rA3.x)) + ((rA4.x+rA5.x)+rA6.x); \
  float awA = ((rA0.y+rA1.y)+(rA2.y+rA3.y)) + ((rA4.y+rA5.y)+rA6.y); \
  float ahB = ((rB0.x+rB1.x)+(rB2.x+rB3.x)) + ((rB4.x+rB5.x)+rB6.x); \
  float awB = ((rB0.y+rB1.y)+(rB2.y+rB3.y)) + ((rB4.y+rB5.y)+rB6.y); \
  if (lane < 60){ \
    part[((2*(u)+4)&7)*60 + g*20 + s] = make_float2(ahA,awA); \
    part[((2*(u)+5)&7)*60 + g*20 + s] = make_float2(ahB,awB); \
  } \
  Hb = HA01k | (unsigned long long)bA; \
  Ht = HA2; \
  mpo = bB; \
}

#define PHASE(u) { if (wid == 0){ W0PHASE(u) } else { W1PHASE(u) } WGBAR(); }

  for (int c = 0; c < NFULL; ++c){
    if (wid == 0){
      const float4* gp = gxp + (size_t)(c+1)*640;
      #pragma unroll
      for (int k=0;k<10;k++) px[k] = gp[k*64 + lane];
    }
    #pragma unroll 1
    for (int p4 = 0; p4 < 4; ++p4){
      const int jb = p4*8;
      PHASE(0) PHASE(1) PHASE(2) PHASE(3)
    }
    if (wid == 0){
      float* outb = out + (size_t)c*(CH*SUBN);
      #pragma unroll
      for (int i=0;i<10;i++){ float v = xpbf[(i*64 + lane)*4 + 3]; outb[i*64 + lane] = v; }
      #pragma unroll
      for (int k=0;k<10;k++) xpb[k*64 + lane] = px[k];
      xcur = xpb[s];
    }
  }
  // tail: 16 steps = 8 phases
  #pragma unroll 1
  for (int p4 = 0; p4 < 2; ++p4){
    const int jb = p4*8;
    PHASE(0) PHASE(1) PHASE(2) PHASE(3)
  }
  if (wid == 0){
    float* outb = out + (size_t)NFULL*(CH*SUBN);
    #pragma unroll
    for (int i=0;i<5;i++){ float v = xpbf[(i*64 + lane)*4 + 3]; outb[i*64 + lane] = v; }
  }
#undef PHASE
#undef W1PHASE
#undef W0PHASE
#undef STEP0
#undef POSC
}

extern "C" void kernel_launch(void* const* d_in, const int* in_sizes, int n_in,
                              void* d_out, int out_size, void* d_ws, size_t ws_size,
                              hipStream_t stream){
  const float* Se    = (const float*)d_in[0];
  const float* Si    = (const float*)d_in[1];
  const float* U     = (const float*)d_in[2];
  const float* Wsyn  = (const float*)d_in[3];
  const float* Whist = (const float*)d_in[4];
  const float* Wprop = (const float*)d_in[5];
  const float* Theta = (const float*)d_in[6];
  const float* Cden  = (const float*)d_in[7];
  float* out = (float*)d_out;
  float* ws  = (float*)d_ws;

  colsum_kernel<<<dim3(T_DATA,2),256,0,stream>>>(Se,Si,ws);
  bounds_kernel<<<(T_PAD*SUBN + 255)/256,256,0,stream>>>(U,ws);
  buildkern_kernel<<<1,256,0,stream>>>(Wsyn,Whist,Wprop,ws);
  lutbuild_kernel<<<(NENT + 255)/256,256,0,stream>>>(ws);
  filter_kernel<<<(T_DATA*SUBN + 255)/256,256,0,stream>>>(Theta,ws);
  scan_kernel<<<1,128,0,stream>>>(ws,Cden,out);
}